// Round 5
// baseline (310.455 us; speedup 1.0000x reference)
//
#include <hip/hip_runtime.h>
#include <hip/hip_bf16.h>

#define TT 512
#define BB 64
#define HH 512
#define KK 16

typedef __attribute__((ext_vector_type(8))) short bf16x8;
typedef __attribute__((ext_vector_type(4))) short bf16x4;
typedef __attribute__((ext_vector_type(4))) float f32x4;

// v_mfma_f32_16x16x16_bf16 — legacy gfx90a spelling, carried forward on gfx950.
// NOTE: do NOT gate on __has_builtin (false in the host pass); call directly.
#define MFMA_K16(A, B, C) __builtin_amdgcn_mfma_f32_16x16x16bf16_1k(A, B, C, 0, 0, 0)

__device__ __forceinline__ unsigned short f2bf(float f) {
    union { __hip_bfloat16 h; unsigned short u; } cvt;
    cvt.h = __float2bfloat16(f);
    return cvt.u;
}

// branch-free RNE f32->bf16 (inputs are finite non-NaN here)
__device__ __forceinline__ short rne_bf(float x) {
    unsigned u = __float_as_uint(x);
    u += 0x7fffu + ((u >> 16) & 1u);
    return (short)(u >> 16);
}

__device__ __forceinline__ float bf2f(short s) {
    return __uint_as_float(((unsigned)(unsigned short)s) << 16);
}

// ---------------------------------------------------------------------------
// prep: W1 -> W1t (bf16 [n][k]); W2 -> W2t (bf16 [n][k]); zero out[0].
// ---------------------------------------------------------------------------
__global__ void prep_kernel(const float* __restrict__ W1, const float* __restrict__ W2,
                            unsigned short* __restrict__ W1t, unsigned short* __restrict__ W2t,
                            float* __restrict__ out) {
    const int bi = blockIdx.x, tx = threadIdx.x;
    if (bi < 64) {
        __shared__ float Ls[64][65];
        const int ti = bi & 7, tj = bi >> 3;
        const int r0 = ti * 64, c0 = tj * 64;
        const int r = tx >> 4, c4 = (tx & 15) * 4;
#pragma unroll
        for (int i = 0; i < 4; ++i) {
            float4 v = *(const float4*)(W1 + (size_t)(r0 + r + 16 * i) * HH + c0 + c4);
            Ls[c4 + 0][r + 16 * i] = v.x;
            Ls[c4 + 1][r + 16 * i] = v.y;
            Ls[c4 + 2][r + 16 * i] = v.z;
            Ls[c4 + 3][r + 16 * i] = v.w;
        }
        __syncthreads();
        const int rn = tx >> 4, k4 = (tx & 15) * 4;
#pragma unroll
        for (int i = 0; i < 4; ++i) {
            const int n = rn + 16 * i;
            ushort4 o;
            o.x = f2bf(Ls[n][k4 + 0]);
            o.y = f2bf(Ls[n][k4 + 1]);
            o.z = f2bf(Ls[n][k4 + 2]);
            o.w = f2bf(Ls[n][k4 + 3]);
            *(ushort4*)(W1t + (size_t)(c0 + n) * HH + r0 + k4) = o;
        }
    } else {
        if (tx == 0) out[0] = 0.0f;
        for (int idx = tx; idx < 16 * HH; idx += 256) {
            const int n = idx >> 9, k = idx & 511;
            W2t[idx] = f2bf(W2[k * KK + n]);
        }
    }
}

// ---------------------------------------------------------------------------
// em = relu(hidden @ W1 + b1) @ W2 + b2, bf16 MFMA both GEMMs, fp32 accum.
// ---------------------------------------------------------------------------
__global__ __launch_bounds__(256, 2)
void em_kernel(const float* __restrict__ hidden, const unsigned short* __restrict__ W1t,
               const float* __restrict__ b1, const unsigned short* __restrict__ W2t,
               const float* __restrict__ b2, float* __restrict__ em) {
    __shared__ unsigned short W2ts[16 * 520];
    __shared__ __align__(16) unsigned char stage[37888];
    unsigned short* As = (unsigned short*)stage;            // [64][40] bf16
    unsigned short* Bs = (unsigned short*)(stage + 5120);   // [512][32] bf16, k-swizzled
    unsigned short* Hb = (unsigned short*)stage;            // [64][264] bf16

    const int tx = threadIdx.x;
    const int w = tx >> 6, lane = tx & 63;
    const int q = lane >> 4, nl = lane & 15;
    const int wm = w >> 1, wn = w & 1;
    const int row0 = blockIdx.x * 64;

    for (int i = tx; i < 16 * 64; i += 256) {
        const int n = i >> 6, kc = i & 63;
        *(bf16x8*)(W2ts + n * 520 + kc * 8) = *(const bf16x8*)(W2t + n * HH + kc * 8);
    }

    f32x4 acc[2][16];
#pragma unroll
    for (int mt = 0; mt < 2; ++mt)
#pragma unroll
        for (int nt = 0; nt < 16; ++nt) acc[mt][nt] = (f32x4){0.f, 0.f, 0.f, 0.f};

    for (int kt = 0; kt < 16; ++kt) {
        const int k0 = kt * 32;
        __syncthreads();
        {
            const int r = tx >> 2, c8 = (tx & 3) * 8;
            const float* src = hidden + (size_t)(row0 + r) * HH + k0 + c8;
            float4 v0 = *(const float4*)(src);
            float4 v1 = *(const float4*)(src + 4);
            bf16x8 o;
            o[0] = (short)f2bf(v0.x); o[1] = (short)f2bf(v0.y);
            o[2] = (short)f2bf(v0.z); o[3] = (short)f2bf(v0.w);
            o[4] = (short)f2bf(v1.x); o[5] = (short)f2bf(v1.y);
            o[6] = (short)f2bf(v1.z); o[7] = (short)f2bf(v1.w);
            *(bf16x8*)(As + r * 40 + c8) = o;
        }
#pragma unroll
        for (int it = 0; it < 8; ++it) {
            const int c = it * 256 + tx;
            const int n = c >> 2, slot = c & 3;
            const int kc = slot ^ ((n >> 1) & 3);
            __builtin_amdgcn_global_load_lds(
                (const __attribute__((address_space(1))) void*)(W1t + (size_t)n * HH + k0 + kc * 8),
                (__attribute__((address_space(3))) void*)(Bs + c * 8),
                16, 0, 0);
        }
        __syncthreads();
        bf16x8 af[2];
#pragma unroll
        for (int mt = 0; mt < 2; ++mt)
            af[mt] = *(const bf16x8*)(As + (32 * wm + 16 * mt + nl) * 40 + q * 8);
#pragma unroll
        for (int nt = 0; nt < 16; ++nt) {
            const int n = 256 * wn + 16 * nt + nl;
            const int slot = q ^ ((n >> 1) & 3);
            bf16x8 bf = *(const bf16x8*)(Bs + n * 32 + slot * 8);
            acc[0][nt] = __builtin_amdgcn_mfma_f32_16x16x32_bf16(af[0], bf, acc[0][nt], 0, 0, 0);
            acc[1][nt] = __builtin_amdgcn_mfma_f32_16x16x32_bf16(af[1], bf, acc[1][nt], 0, 0, 0);
        }
    }

    f32x4 acc2 = (f32x4){0.f, 0.f, 0.f, 0.f};
    for (int c = 0; c < 2; ++c) {
        __syncthreads();
        if (wn == c) {
#pragma unroll
            for (int nt = 0; nt < 16; ++nt) {
                const float bv = b1[c * 256 + 16 * nt + nl];
#pragma unroll
                for (int mt = 0; mt < 2; ++mt) {
#pragma unroll
                    for (int r = 0; r < 4; ++r) {
                        float v = acc[mt][nt][r] + bv;
                        v = v > 0.f ? v : 0.f;
                        const int row = 32 * wm + 16 * mt + q * 4 + r;
                        Hb[row * 264 + nt * 16 + nl] = f2bf(v);
                    }
                }
            }
        }
        __syncthreads();
#pragma unroll
        for (int ks = 0; ks < 8; ++ks) {
            bf16x8 a2 = *(const bf16x8*)(Hb + (16 * w + nl) * 264 + ks * 32 + q * 8);
            bf16x8 b2f = *(const bf16x8*)(W2ts + nl * 520 + c * 256 + ks * 32 + q * 8);
            acc2 = __builtin_amdgcn_mfma_f32_16x16x32_bf16(a2, b2f, acc2, 0, 0, 0);
        }
    }
#pragma unroll
    for (int r = 0; r < 4; ++r) {
        const int row = row0 + 16 * w + q * 4 + r;
        em[(size_t)row * KK + nl] = acc2[r] + b2[nl];
    }
}

// ---------------------------------------------------------------------------
// gold: fully parallel gather-sum. One block per batch; atomicAdd(-gold).
// Uses log(bf16(exp(T))) so the scan's bf16-quantized M cancels in fwd-gold.
// ---------------------------------------------------------------------------
__global__ void gold_kernel(const float* __restrict__ em, const float* __restrict__ trans,
                            const int* __restrict__ lens, const int* __restrict__ tags,
                            float* __restrict__ out) {
    __shared__ float trs[256];
    __shared__ float red[4];
    const int b = blockIdx.x, tid = threadIdx.x;
    trs[tid] = __logf(bf2f(rne_bf(__expf(trans[tid]))));
    __syncthreads();
    const int L = lens[b];
    float acc = 0.f;
    for (int t = tid; t < L; t += 256) {
        const int tg = tags[t * BB + b];
        float v = em[((size_t)t * BB + b) * KK + tg];
        if (t > 0) v += trs[tg * 16 + tags[(t - 1) * BB + b]];
        acc += v;
    }
#pragma unroll
    for (int d = 1; d < 64; d <<= 1) acc += __shfl_xor(acc, d, 64);
    if ((tid & 63) == 0) red[tid >> 6] = acc;
    __syncthreads();
    if (tid == 0) atomicAdd(out, -(red[0] + red[1] + red[2] + red[3]));
}

// ---------------------------------------------------------------------------
// CRF forward scan via MFMA feedback.
//   g' = exp(e_t) .* (M g),  M = bf16(exp(T)),  g kept as MFMA B-fragment.
// 16x16x16 B-frag layout (k=4q+i, n=lane&15) == C/D layout (row=4q+r,
// col=lane&15): the MFMA result feeds back with in-lane ops only. Renorm
// every 4 steps: state-0 value captured (lagged) at t%4==1 via shfl, applied
// by scaling the prefetched exp(e) slot at t%4==0 — off the serial chain.
// 4 blocks x 64 thr: 16 batches per wave (batch = col).
// ---------------------------------------------------------------------------
__global__ void scan_kernel(const float* __restrict__ em, const float* __restrict__ trans,
                            const int* __restrict__ lens, float* __restrict__ out) {
    const int lane = threadIdx.x;
    const int q = lane >> 4, col = lane & 15;
    const int b = blockIdx.x * 16 + col;

    // A-frag: M[m=col][k=4q+i] = exp(T[col][4q+i])
    bf16x4 ma;
    {
        float4 tv = *(const float4*)(trans + col * 16 + 4 * q);
        ma[0] = rne_bf(__expf(tv.x));
        ma[1] = rne_bf(__expf(tv.y));
        ma[2] = rne_bf(__expf(tv.z));
        ma[3] = rne_bf(__expf(tv.w));
    }
    const int Lm1 = lens[b] - 1;

    // prefetch ring: ebuf[s] = exp(em[t]) for this lane's 4 states of batch b
    float4 ebuf[8];
#pragma unroll
    for (int i = 0; i < 8; ++i) {
        float4 v = *(const float4*)(em + ((size_t)i * BB + b) * KK + 4 * q);
        ebuf[i] = make_float4(__expf(v.x), __expf(v.y), __expf(v.z), __expf(v.w));
    }

    // t = 0: g0 = exp(em[0])
    float f0 = ebuf[0].x, f1 = ebuf[0].y, f2 = ebuf[0].z, f3 = ebuf[0].w;
    float Cacc = 0.f;
    float sv0 = f0, sv1 = f1, sv2 = f2, sv3 = f3, svC = 0.f;  // valid iff Lm1==0
    bf16x4 gb;
    gb[0] = rne_bf(f0); gb[1] = rne_bf(f1); gb[2] = rne_bf(f2); gb[3] = rne_bf(f3);
    {   // refill slot 0 with t=8
        float4 v = *(const float4*)(em + ((size_t)8 * BB + b) * KK + 4 * q);
        ebuf[0] = make_float4(__expf(v.x), __expf(v.y), __expf(v.z), __expf(v.w));
    }
    const f32x4 zc = (f32x4){0.f, 0.f, 0.f, 0.f};
    float K = 1.0f;

#define SCAN_STEP(t_, s_, pf_)                                                  \
    {                                                                           \
        if (((t_) & 3) == 0 && (t_) >= 4) { /* apply lagged renorm */           \
            const float Km = fmaxf(K, 1e-30f);                                  \
            const float rk = 1.0f / Km;                                         \
            Cacc += __logf(Km);                                                 \
            ebuf[s_].x *= rk; ebuf[s_].y *= rk;                                 \
            ebuf[s_].z *= rk; ebuf[s_].w *= rk;                                 \
        }                                                                       \
        const float4 ee = ebuf[s_];                                             \
        if (pf_) {                                                              \
            float4 v = *(const float4*)(em + ((size_t)((t_) + 8) * BB + b) * KK + 4 * q); \
            ebuf[s_] = make_float4(__expf(v.x), __expf(v.y), __expf(v.z), __expf(v.w));   \
        }                                                                       \
        f32x4 d = MFMA_K16(ma, gb, zc);                                         \
        f0 = d[0] * ee.x; f1 = d[1] * ee.y;                                     \
        f2 = d[2] * ee.z; f3 = d[3] * ee.w;                                     \
        if (((t_) & 3) == 1) K = __shfl(f0, col, 64); /* lagged capture */      \
        if ((t_) == Lm1) { sv0 = f0; sv1 = f1; sv2 = f2; sv3 = f3; svC = Cacc; }\
        gb[0] = rne_bf(f0); gb[1] = rne_bf(f1);                                 \
        gb[2] = rne_bf(f2); gb[3] = rne_bf(f3);                                 \
    }

    // peeled t = 1..7
#pragma unroll
    for (int s = 1; s < 8; ++s) SCAN_STEP(s, s, true);
    // main t = 8..511
    for (int tb = 8; tb < TT; tb += 8) {
        const bool pf = (tb + 8 < TT);
#pragma unroll
        for (int s = 0; s < 8; ++s) SCAN_STEP(tb + s, s, pf);
    }
#undef SCAN_STEP

    // fwd_b = svC + log(sum over 16 states of sv)   (sv > 0, linear domain)
    float mx = fmaxf(fmaxf(sv0, sv1), fmaxf(sv2, sv3));
    mx = fmaxf(mx, __shfl_xor(mx, 16, 64));
    mx = fmaxf(mx, __shfl_xor(mx, 32, 64));
    const float inv = 1.0f / mx;
    float s = sv0 * inv + sv1 * inv + sv2 * inv + sv3 * inv;
    s += __shfl_xor(s, 16, 64);
    s += __shfl_xor(s, 32, 64);
    float fwd = svC + __logf(mx) + __logf(s);

    // sum fwd over the 16 columns (each q-group holds all 16 batch replicas)
#pragma unroll
    for (int d = 1; d < 16; d <<= 1) fwd += __shfl_xor(fwd, d, 64);
    if (lane == 0) atomicAdd(out, fwd);
}

extern "C" void kernel_launch(void* const* d_in, const int* in_sizes, int n_in,
                              void* d_out, int out_size, void* d_ws, size_t ws_size,
                              hipStream_t stream) {
    const float* hidden = (const float*)d_in[0];
    const float* W1     = (const float*)d_in[1];
    const float* b1     = (const float*)d_in[2];
    const float* W2     = (const float*)d_in[3];
    const float* b2     = (const float*)d_in[4];
    const float* trans  = (const float*)d_in[5];
    const int*   lens   = (const int*)d_in[6];
    const int*   tags   = (const int*)d_in[7];
    float* out = (float*)d_out;

    float* em = (float*)d_ws;
    unsigned short* W1t = (unsigned short*)((char*)d_ws + (size_t)TT * BB * KK * 4);
    unsigned short* W2t = W1t + (size_t)HH * HH;

    prep_kernel<<<65, 256, 0, stream>>>(W1, W2, W1t, W2t, out);
    em_kernel<<<512, 256, 0, stream>>>(hidden, W1t, b1, W2t, b2, em);
    gold_kernel<<<64, 256, 0, stream>>>(em, trans, lens, tags, out);
    scan_kernel<<<4, 64, 0, stream>>>(em, trans, lens, out);
}

// Round 6
// 211.145 us; speedup vs baseline: 1.4703x; 1.4703x over previous
//
#include <hip/hip_runtime.h>
#include <hip/hip_bf16.h>

#define TT 512
#define BB 64
#define HH 512
#define KK 16

typedef __attribute__((ext_vector_type(8))) short bf16x8;
typedef __attribute__((ext_vector_type(4))) short bf16x4;
typedef __attribute__((ext_vector_type(4))) float f32x4;

// v_mfma_f32_16x16x16_bf16 — legacy gfx90a spelling, carried forward on gfx950.
// NOTE: do NOT gate on __has_builtin (false in the host pass); call directly.
#define MFMA_K16(A, B, C) __builtin_amdgcn_mfma_f32_16x16x16bf16_1k(A, B, C, 0, 0, 0)

__device__ __forceinline__ unsigned short f2bf(float f) {
    union { __hip_bfloat16 h; unsigned short u; } cvt;
    cvt.h = __float2bfloat16(f);
    return cvt.u;
}

// branch-free RNE f32->bf16 (inputs are finite non-NaN here)
__device__ __forceinline__ short rne_bf(float x) {
    unsigned u = __float_as_uint(x);
    u += 0x7fffu + ((u >> 16) & 1u);
    return (short)(u >> 16);
}

__device__ __forceinline__ float bf2f(short s) {
    return __uint_as_float(((unsigned)(unsigned short)s) << 16);
}

// ---------------------------------------------------------------------------
// prep: W1 -> W1t (bf16 [n][k]); W2 -> W2t (bf16 [n][k]); zero out[0].
// ---------------------------------------------------------------------------
__global__ void prep_kernel(const float* __restrict__ W1, const float* __restrict__ W2,
                            unsigned short* __restrict__ W1t, unsigned short* __restrict__ W2t,
                            float* __restrict__ out) {
    const int bi = blockIdx.x, tx = threadIdx.x;
    if (bi < 64) {
        __shared__ float Ls[64][65];
        const int ti = bi & 7, tj = bi >> 3;
        const int r0 = ti * 64, c0 = tj * 64;
        const int r = tx >> 4, c4 = (tx & 15) * 4;
#pragma unroll
        for (int i = 0; i < 4; ++i) {
            float4 v = *(const float4*)(W1 + (size_t)(r0 + r + 16 * i) * HH + c0 + c4);
            Ls[c4 + 0][r + 16 * i] = v.x;
            Ls[c4 + 1][r + 16 * i] = v.y;
            Ls[c4 + 2][r + 16 * i] = v.z;
            Ls[c4 + 3][r + 16 * i] = v.w;
        }
        __syncthreads();
        const int rn = tx >> 4, k4 = (tx & 15) * 4;
#pragma unroll
        for (int i = 0; i < 4; ++i) {
            const int n = rn + 16 * i;
            ushort4 o;
            o.x = f2bf(Ls[n][k4 + 0]);
            o.y = f2bf(Ls[n][k4 + 1]);
            o.z = f2bf(Ls[n][k4 + 2]);
            o.w = f2bf(Ls[n][k4 + 3]);
            *(ushort4*)(W1t + (size_t)(c0 + n) * HH + r0 + k4) = o;
        }
    } else {
        if (tx == 0) out[0] = 0.0f;
        for (int idx = tx; idx < 16 * HH; idx += 256) {
            const int n = idx >> 9, k = idx & 511;
            W2t[idx] = f2bf(W2[k * KK + n]);
        }
    }
}

// ---------------------------------------------------------------------------
// em = relu(hidden @ W1 + b1) @ W2 + b2, bf16 MFMA both GEMMs, fp32 accum.
// ---------------------------------------------------------------------------
__global__ __launch_bounds__(256, 2)
void em_kernel(const float* __restrict__ hidden, const unsigned short* __restrict__ W1t,
               const float* __restrict__ b1, const unsigned short* __restrict__ W2t,
               const float* __restrict__ b2, float* __restrict__ em) {
    __shared__ unsigned short W2ts[16 * 520];
    __shared__ __align__(16) unsigned char stage[37888];
    unsigned short* As = (unsigned short*)stage;            // [64][40] bf16
    unsigned short* Bs = (unsigned short*)(stage + 5120);   // [512][32] bf16, k-swizzled
    unsigned short* Hb = (unsigned short*)stage;            // [64][264] bf16

    const int tx = threadIdx.x;
    const int w = tx >> 6, lane = tx & 63;
    const int q = lane >> 4, nl = lane & 15;
    const int wm = w >> 1, wn = w & 1;
    const int row0 = blockIdx.x * 64;

    for (int i = tx; i < 16 * 64; i += 256) {
        const int n = i >> 6, kc = i & 63;
        *(bf16x8*)(W2ts + n * 520 + kc * 8) = *(const bf16x8*)(W2t + n * HH + kc * 8);
    }

    f32x4 acc[2][16];
#pragma unroll
    for (int mt = 0; mt < 2; ++mt)
#pragma unroll
        for (int nt = 0; nt < 16; ++nt) acc[mt][nt] = (f32x4){0.f, 0.f, 0.f, 0.f};

    for (int kt = 0; kt < 16; ++kt) {
        const int k0 = kt * 32;
        __syncthreads();
        {
            const int r = tx >> 2, c8 = (tx & 3) * 8;
            const float* src = hidden + (size_t)(row0 + r) * HH + k0 + c8;
            float4 v0 = *(const float4*)(src);
            float4 v1 = *(const float4*)(src + 4);
            bf16x8 o;
            o[0] = (short)f2bf(v0.x); o[1] = (short)f2bf(v0.y);
            o[2] = (short)f2bf(v0.z); o[3] = (short)f2bf(v0.w);
            o[4] = (short)f2bf(v1.x); o[5] = (short)f2bf(v1.y);
            o[6] = (short)f2bf(v1.z); o[7] = (short)f2bf(v1.w);
            *(bf16x8*)(As + r * 40 + c8) = o;
        }
#pragma unroll
        for (int it = 0; it < 8; ++it) {
            const int c = it * 256 + tx;
            const int n = c >> 2, slot = c & 3;
            const int kc = slot ^ ((n >> 1) & 3);
            __builtin_amdgcn_global_load_lds(
                (const __attribute__((address_space(1))) void*)(W1t + (size_t)n * HH + k0 + kc * 8),
                (__attribute__((address_space(3))) void*)(Bs + c * 8),
                16, 0, 0);
        }
        __syncthreads();
        bf16x8 af[2];
#pragma unroll
        for (int mt = 0; mt < 2; ++mt)
            af[mt] = *(const bf16x8*)(As + (32 * wm + 16 * mt + nl) * 40 + q * 8);
#pragma unroll
        for (int nt = 0; nt < 16; ++nt) {
            const int n = 256 * wn + 16 * nt + nl;
            const int slot = q ^ ((n >> 1) & 3);
            bf16x8 bf = *(const bf16x8*)(Bs + n * 32 + slot * 8);
            acc[0][nt] = __builtin_amdgcn_mfma_f32_16x16x32_bf16(af[0], bf, acc[0][nt], 0, 0, 0);
            acc[1][nt] = __builtin_amdgcn_mfma_f32_16x16x32_bf16(af[1], bf, acc[1][nt], 0, 0, 0);
        }
    }

    f32x4 acc2 = (f32x4){0.f, 0.f, 0.f, 0.f};
    for (int c = 0; c < 2; ++c) {
        __syncthreads();
        if (wn == c) {
#pragma unroll
            for (int nt = 0; nt < 16; ++nt) {
                const float bv = b1[c * 256 + 16 * nt + nl];
#pragma unroll
                for (int mt = 0; mt < 2; ++mt) {
#pragma unroll
                    for (int r = 0; r < 4; ++r) {
                        float v = acc[mt][nt][r] + bv;
                        v = v > 0.f ? v : 0.f;
                        const int row = 32 * wm + 16 * mt + q * 4 + r;
                        Hb[row * 264 + nt * 16 + nl] = f2bf(v);
                    }
                }
            }
        }
        __syncthreads();
#pragma unroll
        for (int ks = 0; ks < 8; ++ks) {
            bf16x8 a2 = *(const bf16x8*)(Hb + (16 * w + nl) * 264 + ks * 32 + q * 8);
            bf16x8 b2f = *(const bf16x8*)(W2ts + nl * 520 + c * 256 + ks * 32 + q * 8);
            acc2 = __builtin_amdgcn_mfma_f32_16x16x32_bf16(a2, b2f, acc2, 0, 0, 0);
        }
    }
#pragma unroll
    for (int r = 0; r < 4; ++r) {
        const int row = row0 + 16 * w + q * 4 + r;
        em[(size_t)row * KK + nl] = acc2[r] + b2[nl];
    }
}

// ---------------------------------------------------------------------------
// gold: fully parallel gather-sum. One block per batch; atomicAdd(-gold).
// Uses log(bf16(exp(T))) so the scan's bf16-quantized M cancels in fwd-gold.
// ---------------------------------------------------------------------------
__global__ void gold_kernel(const float* __restrict__ em, const float* __restrict__ trans,
                            const int* __restrict__ lens, const int* __restrict__ tags,
                            float* __restrict__ out) {
    __shared__ float trs[256];
    __shared__ float red[4];
    const int b = blockIdx.x, tid = threadIdx.x;
    trs[tid] = __logf(bf2f(rne_bf(__expf(trans[tid]))));
    __syncthreads();
    const int L = lens[b];
    float acc = 0.f;
    for (int t = tid; t < L; t += 256) {
        const int tg = tags[t * BB + b];
        float v = em[((size_t)t * BB + b) * KK + tg];
        if (t > 0) v += trs[tg * 16 + tags[(t - 1) * BB + b]];
        acc += v;
    }
#pragma unroll
    for (int d = 1; d < 64; d <<= 1) acc += __shfl_xor(acc, d, 64);
    if ((tid & 63) == 0) red[tid >> 6] = acc;
    __syncthreads();
    if (tid == 0) atomicAdd(out, -(red[0] + red[1] + red[2] + red[3]));
}

// ---------------------------------------------------------------------------
// CRF forward scan via MFMA feedback.
//   g' = exp(e_t) .* (M g),  M = bf16(exp(T)),  g kept as MFMA B-fragment.
// 16x16x16 B-frag layout (k=4q+i, n=lane&15) == C/D layout (row=4q+r,
// col=lane&15): MFMA result feeds back with in-lane ops only.
// ebuf holds RAW em values (load->use distance = 8 steps, latency hidden);
// the 4 exps run at use-time, off the MFMA serial chain. Renorm every 4
// steps in log domain (subtract log K from the one slot), K captured lagged
// via shfl at t%4==1. 4 blocks x 64 thr: 16 batches per wave (batch = col).
// ---------------------------------------------------------------------------
__global__ void scan_kernel(const float* __restrict__ em, const float* __restrict__ trans,
                            const int* __restrict__ lens, float* __restrict__ out) {
    const int lane = threadIdx.x;
    const int q = lane >> 4, col = lane & 15;
    const int b = blockIdx.x * 16 + col;

    // A-frag: M[m=col][k=4q+i] = exp(T[col][4q+i])
    bf16x4 ma;
    {
        float4 tv = *(const float4*)(trans + col * 16 + 4 * q);
        ma[0] = rne_bf(__expf(tv.x));
        ma[1] = rne_bf(__expf(tv.y));
        ma[2] = rne_bf(__expf(tv.z));
        ma[3] = rne_bf(__expf(tv.w));
    }
    const int Lm1 = lens[b] - 1;

    // prefetch ring: ebuf[s] = RAW em[t] for this lane's 4 states of batch b
    float4 ebuf[8];
#pragma unroll
    for (int i = 0; i < 8; ++i)
        ebuf[i] = *(const float4*)(em + ((size_t)i * BB + b) * KK + 4 * q);

    // t = 0: g0 = exp(em[0])
    float f0 = __expf(ebuf[0].x), f1 = __expf(ebuf[0].y);
    float f2 = __expf(ebuf[0].z), f3 = __expf(ebuf[0].w);
    float Cacc = 0.f;
    float sv0 = f0, sv1 = f1, sv2 = f2, sv3 = f3, svC = 0.f;  // valid iff Lm1==0
    bf16x4 gb;
    gb[0] = rne_bf(f0); gb[1] = rne_bf(f1); gb[2] = rne_bf(f2); gb[3] = rne_bf(f3);
    // refill slot 0 with t=8 (raw)
    ebuf[0] = *(const float4*)(em + ((size_t)8 * BB + b) * KK + 4 * q);
    const f32x4 zc = (f32x4){0.f, 0.f, 0.f, 0.f};
    float K = 1.0f;

#define SCAN_STEP(t_, s_, pf_)                                                  \
    {                                                                           \
        float4 eraw = ebuf[s_];                                                 \
        if (pf_) {                                                              \
            ebuf[s_] = *(const float4*)(em + ((size_t)((t_) + 8) * BB + b) * KK + 4 * q); \
        }                                                                       \
        if (((t_) & 3) == 0 && (t_) >= 4) { /* lagged renorm, log-domain */     \
            const float lk = __logf(fmaxf(K, 1e-30f));                          \
            Cacc += lk;                                                         \
            eraw.x -= lk; eraw.y -= lk; eraw.z -= lk; eraw.w -= lk;             \
        }                                                                       \
        const float e0 = __expf(eraw.x), e1 = __expf(eraw.y);                   \
        const float e2 = __expf(eraw.z), e3 = __expf(eraw.w);                   \
        f32x4 d = MFMA_K16(ma, gb, zc);                                         \
        f0 = d[0] * e0; f1 = d[1] * e1; f2 = d[2] * e2; f3 = d[3] * e3;         \
        if (((t_) & 3) == 1) K = __shfl(f0, col, 64); /* lagged capture */      \
        if ((t_) == Lm1) { sv0 = f0; sv1 = f1; sv2 = f2; sv3 = f3; svC = Cacc; }\
        gb[0] = rne_bf(f0); gb[1] = rne_bf(f1);                                 \
        gb[2] = rne_bf(f2); gb[3] = rne_bf(f3);                                 \
    }

    // peeled t = 1..7
#pragma unroll
    for (int s = 1; s < 8; ++s) SCAN_STEP(s, s, true);
    // main t = 8..511
    for (int tb = 8; tb < TT; tb += 8) {
        const bool pf = (tb + 8 < TT);
#pragma unroll
        for (int s = 0; s < 8; ++s) SCAN_STEP(tb + s, s, pf);
    }
#undef SCAN_STEP

    // fwd_b = svC + log(sum over 16 states of sv)   (sv > 0, linear domain)
    float mx = fmaxf(fmaxf(sv0, sv1), fmaxf(sv2, sv3));
    mx = fmaxf(mx, __shfl_xor(mx, 16, 64));
    mx = fmaxf(mx, __shfl_xor(mx, 32, 64));
    const float inv = 1.0f / mx;
    float s = sv0 * inv + sv1 * inv + sv2 * inv + sv3 * inv;
    s += __shfl_xor(s, 16, 64);
    s += __shfl_xor(s, 32, 64);
    float fwd = svC + __logf(mx) + __logf(s);

    // sum fwd over the 16 columns (each q-group holds all 16 batch replicas)
#pragma unroll
    for (int d = 1; d < 16; d <<= 1) fwd += __shfl_xor(fwd, d, 64);
    if (lane == 0) atomicAdd(out, fwd);
}

extern "C" void kernel_launch(void* const* d_in, const int* in_sizes, int n_in,
                              void* d_out, int out_size, void* d_ws, size_t ws_size,
                              hipStream_t stream) {
    const float* hidden = (const float*)d_in[0];
    const float* W1     = (const float*)d_in[1];
    const float* b1     = (const float*)d_in[2];
    const float* W2     = (const float*)d_in[3];
    const float* b2     = (const float*)d_in[4];
    const float* trans  = (const float*)d_in[5];
    const int*   lens   = (const int*)d_in[6];
    const int*   tags   = (const int*)d_in[7];
    float* out = (float*)d_out;

    float* em = (float*)d_ws;
    unsigned short* W1t = (unsigned short*)((char*)d_ws + (size_t)TT * BB * KK * 4);
    unsigned short* W2t = W1t + (size_t)HH * HH;

    prep_kernel<<<65, 256, 0, stream>>>(W1, W2, W1t, W2t, out);
    em_kernel<<<512, 256, 0, stream>>>(hidden, W1t, b1, W2t, b2, em);
    gold_kernel<<<64, 256, 0, stream>>>(em, trans, lens, tags, out);
    scan_kernel<<<4, 64, 0, stream>>>(em, trans, lens, out);
}

// Round 7
// 165.126 us; speedup vs baseline: 1.8801x; 1.2787x over previous
//
#include <hip/hip_runtime.h>
#include <hip/hip_bf16.h>

#define TT 512
#define BB 64
#define HH 512
#define KK 16

typedef __attribute__((ext_vector_type(8))) short bf16x8;
typedef __attribute__((ext_vector_type(4))) short bf16x4;
typedef __attribute__((ext_vector_type(4))) float f32x4;

// v_mfma_f32_16x16x16_bf16 — legacy gfx90a spelling, carried forward on gfx950.
// NOTE: do NOT gate on __has_builtin (false in the host pass); call directly.
#define MFMA_K16(A, B, C) __builtin_amdgcn_mfma_f32_16x16x16bf16_1k(A, B, C, 0, 0, 0)

__device__ __forceinline__ unsigned short f2bf(float f) {
    union { __hip_bfloat16 h; unsigned short u; } cvt;
    cvt.h = __float2bfloat16(f);
    return cvt.u;
}

// branch-free RNE f32->bf16 (inputs are finite non-NaN here)
__device__ __forceinline__ short rne_bf(float x) {
    unsigned u = __float_as_uint(x);
    u += 0x7fffu + ((u >> 16) & 1u);
    return (short)(u >> 16);
}

__device__ __forceinline__ float bf2f(short s) {
    return __uint_as_float(((unsigned)(unsigned short)s) << 16);
}

// ---------------------------------------------------------------------------
// prep: W1 -> W1t (bf16 [n][k]); W2 -> W2t (bf16 [n][k]); zero out[0].
// ---------------------------------------------------------------------------
__global__ void prep_kernel(const float* __restrict__ W1, const float* __restrict__ W2,
                            unsigned short* __restrict__ W1t, unsigned short* __restrict__ W2t,
                            float* __restrict__ out) {
    const int bi = blockIdx.x, tx = threadIdx.x;
    if (bi < 64) {
        __shared__ float Ls[64][65];
        const int ti = bi & 7, tj = bi >> 3;
        const int r0 = ti * 64, c0 = tj * 64;
        const int r = tx >> 4, c4 = (tx & 15) * 4;
#pragma unroll
        for (int i = 0; i < 4; ++i) {
            float4 v = *(const float4*)(W1 + (size_t)(r0 + r + 16 * i) * HH + c0 + c4);
            Ls[c4 + 0][r + 16 * i] = v.x;
            Ls[c4 + 1][r + 16 * i] = v.y;
            Ls[c4 + 2][r + 16 * i] = v.z;
            Ls[c4 + 3][r + 16 * i] = v.w;
        }
        __syncthreads();
        const int rn = tx >> 4, k4 = (tx & 15) * 4;
#pragma unroll
        for (int i = 0; i < 4; ++i) {
            const int n = rn + 16 * i;
            ushort4 o;
            o.x = f2bf(Ls[n][k4 + 0]);
            o.y = f2bf(Ls[n][k4 + 1]);
            o.z = f2bf(Ls[n][k4 + 2]);
            o.w = f2bf(Ls[n][k4 + 3]);
            *(ushort4*)(W1t + (size_t)(c0 + n) * HH + r0 + k4) = o;
        }
    } else {
        if (tx == 0) out[0] = 0.0f;
        for (int idx = tx; idx < 16 * HH; idx += 256) {
            const int n = idx >> 9, k = idx & 511;
            W2t[idx] = f2bf(W2[k * KK + n]);
        }
    }
}

// ---------------------------------------------------------------------------
// em = relu(hidden @ W1 + b1) @ W2 + b2, bf16 MFMA both GEMMs, fp32 accum.
// ---------------------------------------------------------------------------
__global__ __launch_bounds__(256, 2)
void em_kernel(const float* __restrict__ hidden, const unsigned short* __restrict__ W1t,
               const float* __restrict__ b1, const unsigned short* __restrict__ W2t,
               const float* __restrict__ b2, float* __restrict__ em) {
    __shared__ unsigned short W2ts[16 * 520];
    __shared__ __align__(16) unsigned char stage[37888];
    unsigned short* As = (unsigned short*)stage;            // [64][40] bf16
    unsigned short* Bs = (unsigned short*)(stage + 5120);   // [512][32] bf16, k-swizzled
    unsigned short* Hb = (unsigned short*)stage;            // [64][264] bf16

    const int tx = threadIdx.x;
    const int w = tx >> 6, lane = tx & 63;
    const int q = lane >> 4, nl = lane & 15;
    const int wm = w >> 1, wn = w & 1;
    const int row0 = blockIdx.x * 64;

    for (int i = tx; i < 16 * 64; i += 256) {
        const int n = i >> 6, kc = i & 63;
        *(bf16x8*)(W2ts + n * 520 + kc * 8) = *(const bf16x8*)(W2t + n * HH + kc * 8);
    }

    f32x4 acc[2][16];
#pragma unroll
    for (int mt = 0; mt < 2; ++mt)
#pragma unroll
        for (int nt = 0; nt < 16; ++nt) acc[mt][nt] = (f32x4){0.f, 0.f, 0.f, 0.f};

    for (int kt = 0; kt < 16; ++kt) {
        const int k0 = kt * 32;
        __syncthreads();
        {
            const int r = tx >> 2, c8 = (tx & 3) * 8;
            const float* src = hidden + (size_t)(row0 + r) * HH + k0 + c8;
            float4 v0 = *(const float4*)(src);
            float4 v1 = *(const float4*)(src + 4);
            bf16x8 o;
            o[0] = (short)f2bf(v0.x); o[1] = (short)f2bf(v0.y);
            o[2] = (short)f2bf(v0.z); o[3] = (short)f2bf(v0.w);
            o[4] = (short)f2bf(v1.x); o[5] = (short)f2bf(v1.y);
            o[6] = (short)f2bf(v1.z); o[7] = (short)f2bf(v1.w);
            *(bf16x8*)(As + r * 40 + c8) = o;
        }
#pragma unroll
        for (int it = 0; it < 8; ++it) {
            const int c = it * 256 + tx;
            const int n = c >> 2, slot = c & 3;
            const int kc = slot ^ ((n >> 1) & 3);
            __builtin_amdgcn_global_load_lds(
                (const __attribute__((address_space(1))) void*)(W1t + (size_t)n * HH + k0 + kc * 8),
                (__attribute__((address_space(3))) void*)(Bs + c * 8),
                16, 0, 0);
        }
        __syncthreads();
        bf16x8 af[2];
#pragma unroll
        for (int mt = 0; mt < 2; ++mt)
            af[mt] = *(const bf16x8*)(As + (32 * wm + 16 * mt + nl) * 40 + q * 8);
#pragma unroll
        for (int nt = 0; nt < 16; ++nt) {
            const int n = 256 * wn + 16 * nt + nl;
            const int slot = q ^ ((n >> 1) & 3);
            bf16x8 bf = *(const bf16x8*)(Bs + n * 32 + slot * 8);
            acc[0][nt] = __builtin_amdgcn_mfma_f32_16x16x32_bf16(af[0], bf, acc[0][nt], 0, 0, 0);
            acc[1][nt] = __builtin_amdgcn_mfma_f32_16x16x32_bf16(af[1], bf, acc[1][nt], 0, 0, 0);
        }
    }

    f32x4 acc2 = (f32x4){0.f, 0.f, 0.f, 0.f};
    for (int c = 0; c < 2; ++c) {
        __syncthreads();
        if (wn == c) {
#pragma unroll
            for (int nt = 0; nt < 16; ++nt) {
                const float bv = b1[c * 256 + 16 * nt + nl];
#pragma unroll
                for (int mt = 0; mt < 2; ++mt) {
#pragma unroll
                    for (int r = 0; r < 4; ++r) {
                        float v = acc[mt][nt][r] + bv;
                        v = v > 0.f ? v : 0.f;
                        const int row = 32 * wm + 16 * mt + q * 4 + r;
                        Hb[row * 264 + nt * 16 + nl] = f2bf(v);
                    }
                }
            }
        }
        __syncthreads();
#pragma unroll
        for (int ks = 0; ks < 8; ++ks) {
            bf16x8 a2 = *(const bf16x8*)(Hb + (16 * w + nl) * 264 + ks * 32 + q * 8);
            bf16x8 b2f = *(const bf16x8*)(W2ts + nl * 520 + c * 256 + ks * 32 + q * 8);
            acc2 = __builtin_amdgcn_mfma_f32_16x16x32_bf16(a2, b2f, acc2, 0, 0, 0);
        }
    }
#pragma unroll
    for (int r = 0; r < 4; ++r) {
        const int row = row0 + 16 * w + q * 4 + r;
        em[(size_t)row * KK + nl] = acc2[r] + b2[nl];
    }
}

// ---------------------------------------------------------------------------
// gold: parallel gather-sum, coalesced: thread=(t,b), b innermost.
// Uses log(bf16(exp(T))) so the scan's bf16-quantized M cancels in fwd-gold.
// ---------------------------------------------------------------------------
__global__ void gold_kernel(const float* __restrict__ em, const float* __restrict__ trans,
                            const int* __restrict__ lens, const int* __restrict__ tags,
                            float* __restrict__ out) {
    __shared__ float trs[256];
    __shared__ float red[4];
    const int tid = threadIdx.x;
    trs[tid] = __logf(bf2f(rne_bf(__expf(trans[tid]))));
    __syncthreads();
    const int idx = blockIdx.x * 256 + tid;
    const int t = idx >> 6, b = idx & 63;
    const int L = lens[b];
    float v = 0.0f;
    if (t < L) {
        const int tg = tags[t * BB + b];
        v = em[((size_t)t * BB + b) * KK + tg];
        if (t > 0) v += trs[tg * 16 + tags[(t - 1) * BB + b]];
    }
#pragma unroll
    for (int dd = 1; dd < 64; dd <<= 1) v += __shfl_xor(v, dd, 64);
    if ((tid & 63) == 0) red[tid >> 6] = v;
    __syncthreads();
    if (tid == 0) atomicAdd(out, -(red[0] + red[1] + red[2] + red[3]));
}

// ---------------------------------------------------------------------------
// Phase A: chunked matrix-product scan. 512 waves = 8 chunks x 64 batches.
// Each wave: P_c = prod_{t in chunk} A_t, A_t = diag(exp(e_t)) * M (bf16),
// M = bf16(exp(T)); chunk 0 absorbs t=0 as diag(exp(e_0)) (M=I for that step).
// Feedback: D-layout == B-frag layout -> in-lane rne+pack only on the chain.
// Renorm every 4 steps (lagged P[0][0] capture, folded into exp(e) off-chain).
// The wave whose chunk contains Lm1 also saves the partial product (fp32).
// ---------------------------------------------------------------------------
__global__ void chunk_kernel(const float* __restrict__ em, const float* __restrict__ trans,
                             const int* __restrict__ lens,
                             float* __restrict__ Pfull, float* __restrict__ Cfull,
                             float* __restrict__ Ppart, float* __restrict__ Cpart) {
    const int tx = threadIdx.x;
    const int id = blockIdx.x * 4 + (tx >> 6);   // 0..511
    const int lane = tx & 63, q = lane >> 4, col = lane & 15;
    const int b = id >> 3, c = id & 7;

    // A-row factors: lane holds row m=col of M: mf[i] = bf16(exp(T[col][4q+i]))
    float mf[4];
    {
        float4 tv = *(const float4*)(trans + col * 16 + 4 * q);
        mf[0] = bf2f(rne_bf(__expf(tv.x)));
        mf[1] = bf2f(rne_bf(__expf(tv.y)));
        mf[2] = bf2f(rne_bf(__expf(tv.z)));
        mf[3] = bf2f(rne_bf(__expf(tv.w)));
    }
    const int Lm1 = lens[b] - 1;
    const int tb0 = 64 * c;

    // prefetch ring: raw em values, load->use distance 8 steps
    float ebuf[8];
#pragma unroll
    for (int i = 0; i < 8; ++i)
        ebuf[i] = em[(size_t)((tb0 + i) * BB + b) * KK + col];

    // B-frag = identity: B[k=4q+i][n=col]
    bf16x4 gb;
#pragma unroll
    for (int i = 0; i < 4; ++i)
        gb[i] = (4 * q + i == col) ? rne_bf(1.0f) : (short)0;

    const f32x4 zc = (f32x4){0.f, 0.f, 0.f, 0.f};
    f32x4 d = (f32x4){0.f, 0.f, 0.f, 0.f};
    float K = 1.0f, rk = 1.0f, lk = 0.0f, Cacc = 0.0f;

    for (int sb = 0; sb < 64; sb += 8) {
        const bool refill = (sb < 56);
#pragma unroll
        for (int s8 = 0; s8 < 8; ++s8) {
            const int t = tb0 + sb + s8;
            const float eraw = ebuf[s8];
            if (refill)
                ebuf[s8] = em[(size_t)((t + 8) * BB + b) * KK + col];
            float ev = __expf(eraw);
            if ((s8 & 3) == 0 && (sb + s8) >= 4) {  // lagged renorm (off-chain)
                ev *= rk;
                Cacc += lk;
            }
            bf16x4 af;
            af[0] = rne_bf(ev * mf[0]); af[1] = rne_bf(ev * mf[1]);
            af[2] = rne_bf(ev * mf[2]); af[3] = rne_bf(ev * mf[3]);
            if (s8 == 0) {
                if (sb == 0 && c == 0) {  // t=0: A_0 = diag(exp(e_0))
#pragma unroll
                    for (int i = 0; i < 4; ++i)
                        af[i] = (4 * q + i == col) ? rne_bf(ev) : (short)0;
                }
            }
            d = MFMA_K16(af, gb, zc);
            if ((s8 & 3) == 1) {  // lagged capture of P[0][0]
                K = __shfl(d[0], 0, 64);
                const float Km = fmaxf(K, 1e-30f);
                rk = 1.0f / Km;
                lk = __logf(Km);
            }
            if (t == Lm1) {  // save partial product (fp32) + its scale
#pragma unroll
                for (int r = 0; r < 4; ++r)
                    Ppart[b * 256 + (4 * q + r) * 16 + col] = d[r];
                if (lane == 0) Cpart[b] = Cacc;
            }
            gb[0] = rne_bf(d[0]); gb[1] = rne_bf(d[1]);
            gb[2] = rne_bf(d[2]); gb[3] = rne_bf(d[3]);
        }
    }
#pragma unroll
    for (int r = 0; r < 4; ++r)
        Pfull[(size_t)(b * 8 + c) * 256 + (4 * q + r) * 16 + col] = d[r];
    if (lane == 0) Cfull[b * 8 + c] = Cacc;
}

// ---------------------------------------------------------------------------
// Phase B: per batch, ones-vector through P_0..P_{c*-1}, then partial P-hat.
// fp32 matvecs, per-chunk max-normalization, final lse. 16 blocks x 64 thr.
// ---------------------------------------------------------------------------
__global__ void combine_kernel(const int* __restrict__ lens,
                               const float* __restrict__ Pfull, const float* __restrict__ Cfull,
                               const float* __restrict__ Ppart, const float* __restrict__ Cpart,
                               float* __restrict__ out) {
    const int lane = threadIdx.x;
    const int grp = lane >> 4, j = lane & 15;
    const int b = blockIdx.x * 4 + grp;
    const int base = grp << 4;
    const int cstar = (lens[b] - 1) >> 6;

    float g = 1.0f, acc = 0.0f;
    for (int c = 0; c < 8; ++c) {
        const bool act = (c <= cstar);
        const float* P = (c < cstar) ? (Pfull + (size_t)(b * 8 + c) * 256)
                                     : (Ppart + b * 256);
        float gn = 0.0f;
#pragma unroll
        for (int k = 0; k < 16; ++k) {
            const float gk = __shfl(g, base + k, 64);
            gn += P[j * 16 + k] * gk;
        }
        if (act) {
            float m = gn;
#pragma unroll
            for (int dd = 1; dd < 16; dd <<= 1) m = fmaxf(m, __shfl_xor(m, dd, 64));
            g = gn / m;
            acc += __logf(m) + ((c < cstar) ? Cfull[b * 8 + c] : Cpart[b]);
        }
    }
    float ssum = g;
#pragma unroll
    for (int dd = 1; dd < 16; dd <<= 1) ssum += __shfl_xor(ssum, dd, 64);
    const float fwd = acc + __logf(ssum);
    if (j == 0) atomicAdd(out, fwd);
}

extern "C" void kernel_launch(void* const* d_in, const int* in_sizes, int n_in,
                              void* d_out, int out_size, void* d_ws, size_t ws_size,
                              hipStream_t stream) {
    const float* hidden = (const float*)d_in[0];
    const float* W1     = (const float*)d_in[1];
    const float* b1     = (const float*)d_in[2];
    const float* W2     = (const float*)d_in[3];
    const float* b2     = (const float*)d_in[4];
    const float* trans  = (const float*)d_in[5];
    const int*   lens   = (const int*)d_in[6];
    const int*   tags   = (const int*)d_in[7];
    float* out = (float*)d_out;

    char* ws = (char*)d_ws;
    float* em = (float*)ws;                                   // 2 MB
    unsigned short* W1t = (unsigned short*)(ws + 2097152);    // 512 KB
    unsigned short* W2t = (unsigned short*)(ws + 2621440);    // 16 KB
    float* Pfull = (float*)(ws + 2637824);                    // 512 KB
    float* Cfull = (float*)(ws + 3162112);                    // 2 KB
    float* Ppart = (float*)(ws + 3164160);                    // 64 KB
    float* Cpart = (float*)(ws + 3229696);                    // 256 B

    prep_kernel<<<65, 256, 0, stream>>>(W1, W2, W1t, W2t, out);
    em_kernel<<<512, 256, 0, stream>>>(hidden, W1t, b1, W2t, b2, em);
    gold_kernel<<<128, 256, 0, stream>>>(em, trans, lens, tags, out);
    chunk_kernel<<<128, 256, 0, stream>>>(em, trans, lens, Pfull, Cfull, Ppart, Cpart);
    combine_kernel<<<16, 64, 0, stream>>>(lens, Pfull, Cfull, Ppart, Cpart, out);
}